// Round 1
// baseline (685.246 us; speedup 1.0000x reference)
//
#include <hip/hip_runtime.h>

#define NN 100000
#define NE 1600000
#define HID 32

// ---- degree count: one thread per edge, int atomic on dst ----
__global__ void count_deg_kernel(const int* __restrict__ dst, int* __restrict__ deg) {
    int e = blockIdx.x * blockDim.x + threadIdx.x;
    if (e < NE) atomicAdd(&deg[dst[e]], 1);
}

// ---- dinv = rsqrt(deg + 1)  (self loop guarantees > 0) ----
__global__ void dinv_kernel(const int* __restrict__ deg, float* __restrict__ dinv) {
    int n = blockIdx.x * blockDim.x + threadIdx.x;
    if (n < NN) dinv[n] = rsqrtf((float)(deg[n] + 1));
}

// ---- fc1: h[n,j] = relu(x[n,0]*W[0,j] + x[n,1]*W[1,j] + b[j]) ----
__global__ void fc1_kernel(const float* __restrict__ x, const float* __restrict__ W,
                           const float* __restrict__ b, float* __restrict__ h) {
    int gid = blockIdx.x * blockDim.x + threadIdx.x;
    if (gid >= NN * HID) return;
    int n = gid >> 5, j = gid & 31;
    float v = x[2 * n] * W[j] + x[2 * n + 1] * W[HID + j] + b[j];
    h[gid] = fmaxf(v, 0.f);
}

// ---- in-place 32x32 GEMM per node block (8 nodes / 256-thread block) ----
// SCALE: multiply row result by dinv[n] (pre-scale by dinv[src] for scatter)
// BIASRELU: add bias[j] and relu (used for fc2)
template <bool SCALE, bool BIASRELU>
__global__ void gemm32_kernel(float* __restrict__ h, const float* __restrict__ W,
                              const float* __restrict__ dinv, const float* __restrict__ bias) {
    __shared__ float wl[HID * HID];
    __shared__ float hs[256];
    int tid = threadIdx.x;
    int base = blockIdx.x * 256;  // 8 nodes * 32 ch
#pragma unroll
    for (int i = 0; i < 4; ++i) wl[tid + 256 * i] = W[tid + 256 * i];
    hs[tid] = h[base + tid];
    __syncthreads();
    int ln = tid >> 5;  // local node 0..7
    int j = tid & 31;
    float acc = 0.f;
#pragma unroll
    for (int k = 0; k < HID; ++k) acc += hs[ln * HID + k] * wl[k * HID + j];
    if (SCALE) {
        int n = (base >> 5) + ln;
        acc *= dinv[n];
    }
    if (BIASRELU) acc = fmaxf(acc + bias[j], 0.f);
    h[base + tid] = acc;
}

// ---- self-loop init: out[n,j] = u[n,j] * dinv[n]  (u already has one dinv factor) ----
__global__ void self_kernel(const float* __restrict__ u, const float* __restrict__ dinv,
                            float* __restrict__ out) {
    int gid = blockIdx.x * blockDim.x + threadIdx.x;
    if (gid >= NN * HID) return;
    out[gid] = u[gid] * dinv[gid >> 5];
}

// ---- edge scatter: out[d,j] += u[s,j] * dinv[d]; one thread per (edge, channel) ----
__global__ void scatter_kernel(const int* __restrict__ src, const int* __restrict__ dst,
                               const float* __restrict__ u, const float* __restrict__ dinv,
                               float* __restrict__ out) {
    int gid = blockIdx.x * blockDim.x + threadIdx.x;
    if (gid >= NE * HID) return;
    int e = gid >> 5, j = gid & 31;
    int s = src[e], d = dst[e];
    atomicAdd(&out[d * HID + j], u[s * HID + j] * dinv[d]);
}

// ---- bias + relu pass after aggregation ----
__global__ void bias_relu_kernel(float* __restrict__ h, const float* __restrict__ b) {
    int gid = blockIdx.x * blockDim.x + threadIdx.x;
    if (gid >= NN * HID) return;
    h[gid] = fmaxf(h[gid] + b[gid & 31], 0.f);
}

// ---- fc3: out[n] = sum_j h[n,j]*W[j] + b; width-32 shuffle reduce ----
__global__ void fc3_kernel(const float* __restrict__ h, const float* __restrict__ W,
                           const float* __restrict__ b, float* __restrict__ out) {
    int gid = blockIdx.x * blockDim.x + threadIdx.x;
    int n = gid >> 5, j = gid & 31;
    float p = 0.f;
    if (n < NN) p = h[gid] * W[j];
#pragma unroll
    for (int m = 16; m; m >>= 1) p += __shfl_xor(p, m, 64);
    if (j == 0 && n < NN) out[n] = p + b[0];
}

extern "C" void kernel_launch(void* const* d_in, const int* in_sizes, int n_in,
                              void* d_out, int out_size, void* d_ws, size_t ws_size,
                              hipStream_t stream) {
    const float* x     = (const float*)d_in[0];
    const int*   ei    = (const int*)d_in[1];
    const float* fc1_W = (const float*)d_in[2];
    const float* fc1_b = (const float*)d_in[3];
    const float* c1_W  = (const float*)d_in[4];
    const float* c1_b  = (const float*)d_in[5];
    const float* c2_W  = (const float*)d_in[6];
    const float* c2_b  = (const float*)d_in[7];
    const float* c3_W  = (const float*)d_in[8];
    const float* c3_b  = (const float*)d_in[9];
    const float* fc2_W = (const float*)d_in[10];
    const float* fc2_b = (const float*)d_in[11];
    const float* fc3_W = (const float*)d_in[12];
    const float* fc3_b = (const float*)d_in[13];

    const int* src = ei;       // edge_index[0]
    const int* dst = ei + NE;  // edge_index[1]

    float* ws   = (float*)d_ws;
    float* dinv = ws;                 // N floats
    int*   deg  = (int*)(ws + NN);    // N ints
    float* hA   = ws + 2 * NN;        // N*32 floats
    float* hB   = hA + NN * HID;      // N*32 floats

    float* out = (float*)d_out;

    const int B = 256;
    const int gN   = (NN + B - 1) / B;          // node-grid
    const int gNH  = (NN * HID + B - 1) / B;    // node*ch grid (=12500)
    const int gE   = (NE + B - 1) / B;          // edge grid
    const int gEH  = (NE * HID + B - 1) / B;    // edge*ch grid (=200000)

    // degree + dinv (recomputed every call: no cross-call state)
    hipMemsetAsync(deg, 0, NN * sizeof(int), stream);
    count_deg_kernel<<<gE, B, 0, stream>>>(dst, deg);
    dinv_kernel<<<gN, B, 0, stream>>>(deg, dinv);

    // fc1 -> hA
    fc1_kernel<<<gNH, B, 0, stream>>>(x, fc1_W, fc1_b, hA);

    // ---- conv1: hA -> hB ----
    gemm32_kernel<true, false><<<gNH, B, 0, stream>>>(hA, c1_W, dinv, nullptr);
    self_kernel<<<gNH, B, 0, stream>>>(hA, dinv, hB);
    scatter_kernel<<<gEH, B, 0, stream>>>(src, dst, hA, dinv, hB);
    bias_relu_kernel<<<gNH, B, 0, stream>>>(hB, c1_b);

    // ---- conv2: hB -> hA ----
    gemm32_kernel<true, false><<<gNH, B, 0, stream>>>(hB, c2_W, dinv, nullptr);
    self_kernel<<<gNH, B, 0, stream>>>(hB, dinv, hA);
    scatter_kernel<<<gEH, B, 0, stream>>>(src, dst, hB, dinv, hA);
    bias_relu_kernel<<<gNH, B, 0, stream>>>(hA, c2_b);

    // ---- conv3: hA -> hB ----
    gemm32_kernel<true, false><<<gNH, B, 0, stream>>>(hA, c3_W, dinv, nullptr);
    self_kernel<<<gNH, B, 0, stream>>>(hA, dinv, hB);
    scatter_kernel<<<gEH, B, 0, stream>>>(src, dst, hA, dinv, hB);
    bias_relu_kernel<<<gNH, B, 0, stream>>>(hB, c3_b);

    // fc2 (in-place on hB, bias+relu fused)
    gemm32_kernel<false, true><<<gNH, B, 0, stream>>>(hB, fc2_W, nullptr, fc2_b);

    // fc3 -> d_out
    fc3_kernel<<<gNH, B, 0, stream>>>(hB, fc3_W, fc3_b, out);
}

// Round 2
// 528.235 us; speedup vs baseline: 1.2972x; 1.2972x over previous
//
#include <hip/hip_runtime.h>

#define NN 100000
#define NE 1600000
#define HID 32

// ---- degree count: one thread per edge, int atomic on dst ----
__global__ void count_deg_kernel(const int* __restrict__ dst, int* __restrict__ deg) {
    int e = blockIdx.x * blockDim.x + threadIdx.x;
    if (e < NE) atomicAdd(&deg[dst[e]], 1);
}

// ---- dinv = rsqrt(deg + 1)  (self loop guarantees > 0) ----
__global__ void dinv_kernel(const int* __restrict__ deg, float* __restrict__ dinv) {
    int n = blockIdx.x * blockDim.x + threadIdx.x;
    if (n < NN) dinv[n] = rsqrtf((float)(deg[n] + 1));
}

// ================= exclusive scan of deg -> rowstart (3 kernels) =================
// scan1: 1024 elems/block (256 thr x 4), write per-elem exclusive-within-block + blocksum
__global__ void scan1_kernel(const int* __restrict__ deg, int* __restrict__ pre,
                             int* __restrict__ bsum) {
    __shared__ int ls[256];
    int t = threadIdx.x;
    int base = blockIdx.x * 1024 + t * 4;
    int v0 = (base + 0 < NN) ? deg[base + 0] : 0;
    int v1 = (base + 1 < NN) ? deg[base + 1] : 0;
    int v2 = (base + 2 < NN) ? deg[base + 2] : 0;
    int v3 = (base + 3 < NN) ? deg[base + 3] : 0;
    int s = v0 + v1 + v2 + v3;
    ls[t] = s;
    __syncthreads();
    for (int off = 1; off < 256; off <<= 1) {
        int x = (t >= off) ? ls[t - off] : 0;
        __syncthreads();
        ls[t] += x;
        __syncthreads();
    }
    int excl = ls[t] - s;
    if (t == 255) bsum[blockIdx.x] = ls[255];
    int run = excl;
    if (base + 0 < NN) pre[base + 0] = run; run += v0;
    if (base + 1 < NN) pre[base + 1] = run; run += v1;
    if (base + 2 < NN) pre[base + 2] = run; run += v2;
    if (base + 3 < NN) pre[base + 3] = run;
}

// scan2: single block, exclusive scan of nb (<=128) block sums
__global__ void scan2_kernel(int* __restrict__ bsum, int nb) {
    __shared__ int ls[128];
    int t = threadIdx.x;
    int v = (t < nb) ? bsum[t] : 0;
    ls[t] = v;
    __syncthreads();
    for (int off = 1; off < 128; off <<= 1) {
        int x = (t >= off) ? ls[t - off] : 0;
        __syncthreads();
        ls[t] += x;
        __syncthreads();
    }
    if (t < nb) bsum[t] = ls[t] - v;
}

// scan3: rowstart[n] = pre[n] + bsum[block(n)]; cursor copy; rowstart[NN]=NE
__global__ void scan3_kernel(const int* __restrict__ pre, const int* __restrict__ bsum,
                             int* __restrict__ rowstart, int* __restrict__ cursor) {
    int n = blockIdx.x * blockDim.x + threadIdx.x;
    if (n < NN) {
        int r = pre[n] + bsum[n >> 10];
        rowstart[n] = r;
        cursor[n] = r;
    }
    if (n == 0) rowstart[NN] = NE;
}

// ---- bin edges by dst: srcidx[cursor[d]++] = src[e] ----
__global__ void bin_kernel(const int* __restrict__ src, const int* __restrict__ dst,
                           int* __restrict__ cursor, int* __restrict__ srcidx) {
    int e = blockIdx.x * blockDim.x + threadIdx.x;
    if (e >= NE) return;
    int d = dst[e];
    int p = atomicAdd(&cursor[d], 1);
    srcidx[p] = src[e];
}

// ---- fc1: h[n,j] = relu(x[n,0]*W[0,j] + x[n,1]*W[1,j] + b[j]) ----
__global__ void fc1_kernel(const float* __restrict__ x, const float* __restrict__ W,
                           const float* __restrict__ b, float* __restrict__ h) {
    int gid = blockIdx.x * blockDim.x + threadIdx.x;
    if (gid >= NN * HID) return;
    int n = gid >> 5, j = gid & 31;
    float v = x[2 * n] * W[j] + x[2 * n + 1] * W[HID + j] + b[j];
    h[gid] = fmaxf(v, 0.f);
}

// ---- in-place 32x32 GEMM per node block (8 nodes / 256-thread block) ----
template <bool SCALE, bool BIASRELU>
__global__ void gemm32_kernel(float* __restrict__ h, const float* __restrict__ W,
                              const float* __restrict__ dinv, const float* __restrict__ bias) {
    __shared__ float wl[HID * HID];
    __shared__ float hs[256];
    int tid = threadIdx.x;
    int base = blockIdx.x * 256;  // 8 nodes * 32 ch
#pragma unroll
    for (int i = 0; i < 4; ++i) wl[tid + 256 * i] = W[tid + 256 * i];
    hs[tid] = h[base + tid];
    __syncthreads();
    int ln = tid >> 5;
    int j = tid & 31;
    float acc = 0.f;
#pragma unroll
    for (int k = 0; k < HID; ++k) acc += hs[ln * HID + k] * wl[k * HID + j];
    if (SCALE) {
        int n = (base >> 5) + ln;
        acc *= dinv[n];
    }
    if (BIASRELU) acc = fmaxf(acc + bias[j], 0.f);
    h[base + tid] = acc;
}

// ---- CSR gather aggregate: out[n,j] = relu(dinv[n]*(u[n,j] + sum_{s in in(n)} u[s,j]) + b[j]) ----
__global__ void gather_kernel(const float* __restrict__ u, const int* __restrict__ rowstart,
                              const int* __restrict__ srcidx, const float* __restrict__ dinv,
                              const float* __restrict__ bias, float* __restrict__ out) {
    int gid = blockIdx.x * blockDim.x + threadIdx.x;
    if (gid >= NN * HID) return;
    int n = gid >> 5, j = gid & 31;
    float acc = u[(n << 5) + j];  // self loop (u already carries dinv[src]=dinv[n])
    int beg = rowstart[n], end = rowstart[n + 1];
    for (int e = beg; e < end; ++e) {
        int s = srcidx[e];
        acc += u[(s << 5) + j];
    }
    acc = acc * dinv[n] + bias[j];
    out[gid] = fmaxf(acc, 0.f);
}

// ---- fc3: out[n] = sum_j h[n,j]*W[j] + b ----
__global__ void fc3_kernel(const float* __restrict__ h, const float* __restrict__ W,
                           const float* __restrict__ b, float* __restrict__ out) {
    int gid = blockIdx.x * blockDim.x + threadIdx.x;
    int n = gid >> 5, j = gid & 31;
    float p = 0.f;
    if (n < NN) p = h[gid] * W[j];
#pragma unroll
    for (int m = 16; m; m >>= 1) p += __shfl_xor(p, m, 64);
    if (j == 0 && n < NN) out[n] = p + b[0];
}

extern "C" void kernel_launch(void* const* d_in, const int* in_sizes, int n_in,
                              void* d_out, int out_size, void* d_ws, size_t ws_size,
                              hipStream_t stream) {
    const float* x     = (const float*)d_in[0];
    const int*   ei    = (const int*)d_in[1];
    const float* fc1_W = (const float*)d_in[2];
    const float* fc1_b = (const float*)d_in[3];
    const float* c1_W  = (const float*)d_in[4];
    const float* c1_b  = (const float*)d_in[5];
    const float* c2_W  = (const float*)d_in[6];
    const float* c2_b  = (const float*)d_in[7];
    const float* c3_W  = (const float*)d_in[8];
    const float* c3_b  = (const float*)d_in[9];
    const float* fc2_W = (const float*)d_in[10];
    const float* fc2_b = (const float*)d_in[11];
    const float* fc3_W = (const float*)d_in[12];
    const float* fc3_b = (const float*)d_in[13];

    const int* src = ei;
    const int* dst = ei + NE;

    // workspace layout (floats unless noted)
    float* ws       = (float*)d_ws;
    float* dinv     = ws;                      // NN
    int*   deg      = (int*)(ws + NN);         // NN
    float* hA       = ws + 2 * NN;             // NN*32
    float* hB       = hA + NN * HID;           // NN*32
    int*   rowstart = (int*)(hB + NN * HID);   // NN+1
    int*   cursor   = rowstart + NN + 1;       // NN
    int*   pre      = cursor + NN;             // NN
    int*   bsum     = pre + NN;                // 128
    int*   srcidx   = bsum + 128;              // NE

    float* out = (float*)d_out;

    const int B = 256;
    const int gN  = (NN + B - 1) / B;
    const int gNH = (NN * HID + B - 1) / B;
    const int gE  = (NE + B - 1) / B;
    const int nScanBlk = (NN + 1023) / 1024;   // 98

    // ---- build CSR (per call; deterministic) ----
    hipMemsetAsync(deg, 0, NN * sizeof(int), stream);
    count_deg_kernel<<<gE, B, 0, stream>>>(dst, deg);
    dinv_kernel<<<gN, B, 0, stream>>>(deg, dinv);
    scan1_kernel<<<nScanBlk, 256, 0, stream>>>(deg, pre, bsum);
    scan2_kernel<<<1, 128, 0, stream>>>(bsum, nScanBlk);
    scan3_kernel<<<gN, B, 0, stream>>>(pre, bsum, rowstart, cursor);
    bin_kernel<<<gE, B, 0, stream>>>(src, dst, cursor, srcidx);

    // fc1 -> hA
    fc1_kernel<<<gNH, B, 0, stream>>>(x, fc1_W, fc1_b, hA);

    // ---- conv1: hA -> hB ----
    gemm32_kernel<true, false><<<gNH, B, 0, stream>>>(hA, c1_W, dinv, nullptr);
    gather_kernel<<<gNH, B, 0, stream>>>(hA, rowstart, srcidx, dinv, c1_b, hB);

    // ---- conv2: hB -> hA ----
    gemm32_kernel<true, false><<<gNH, B, 0, stream>>>(hB, c2_W, dinv, nullptr);
    gather_kernel<<<gNH, B, 0, stream>>>(hB, rowstart, srcidx, dinv, c2_b, hA);

    // ---- conv3: hA -> hB ----
    gemm32_kernel<true, false><<<gNH, B, 0, stream>>>(hA, c3_W, dinv, nullptr);
    gather_kernel<<<gNH, B, 0, stream>>>(hA, rowstart, srcidx, dinv, c3_b, hB);

    // fc2 (in-place on hB, bias+relu fused)
    gemm32_kernel<false, true><<<gNH, B, 0, stream>>>(hB, fc2_W, nullptr, fc2_b);

    // fc3 -> d_out
    fc3_kernel<<<gNH, B, 0, stream>>>(hB, fc3_W, fc3_b, out);
}

// Round 3
// 460.003 us; speedup vs baseline: 1.4897x; 1.1483x over previous
//
#include <hip/hip_runtime.h>

#define NN 100000
#define NE 1600000
#define HID 32
#define NBK 98        // ceil(NN/1024) buckets of 1024 nodes
#define CHUNK 4096    // edges per partition block

// ---- degree count: one thread per edge, int atomic on dst ----
__global__ void count_deg_kernel(const int* __restrict__ dst, int* __restrict__ deg) {
    int e = blockIdx.x * blockDim.x + threadIdx.x;
    if (e < NE) atomicAdd(&deg[dst[e]], 1);
}

// ---- dinv = rsqrt(deg + 1)  (self loop guarantees > 0) ----
__global__ void dinv_kernel(const int* __restrict__ deg, float* __restrict__ dinv) {
    int n = blockIdx.x * blockDim.x + threadIdx.x;
    if (n < NN) dinv[n] = rsqrtf((float)(deg[n] + 1));
}

// ================= exclusive scan of deg -> rowstart =================
__global__ void scan1_kernel(const int* __restrict__ deg, int* __restrict__ pre,
                             int* __restrict__ bsum) {
    __shared__ int ls[256];
    int t = threadIdx.x;
    int base = blockIdx.x * 1024 + t * 4;
    int v0 = (base + 0 < NN) ? deg[base + 0] : 0;
    int v1 = (base + 1 < NN) ? deg[base + 1] : 0;
    int v2 = (base + 2 < NN) ? deg[base + 2] : 0;
    int v3 = (base + 3 < NN) ? deg[base + 3] : 0;
    int s = v0 + v1 + v2 + v3;
    ls[t] = s;
    __syncthreads();
    for (int off = 1; off < 256; off <<= 1) {
        int x = (t >= off) ? ls[t - off] : 0;
        __syncthreads();
        ls[t] += x;
        __syncthreads();
    }
    int excl = ls[t] - s;
    if (t == 255) bsum[blockIdx.x] = ls[255];
    int run = excl;
    if (base + 0 < NN) pre[base + 0] = run; run += v0;
    if (base + 1 < NN) pre[base + 1] = run; run += v1;
    if (base + 2 < NN) pre[base + 2] = run; run += v2;
    if (base + 3 < NN) pre[base + 3] = run;
}

__global__ void scan2_kernel(int* __restrict__ bsum, int nb) {
    __shared__ int ls[128];
    int t = threadIdx.x;
    int v = (t < nb) ? bsum[t] : 0;
    ls[t] = v;
    __syncthreads();
    for (int off = 1; off < 128; off <<= 1) {
        int x = (t >= off) ? ls[t - off] : 0;
        __syncthreads();
        ls[t] += x;
        __syncthreads();
    }
    if (t < nb) bsum[t] = ls[t] - v;
}

// rowstart/cursor + per-bucket allocation cursor (bcur[b] = rowstart[b*1024])
__global__ void scan3_kernel(const int* __restrict__ pre, const int* __restrict__ bsum,
                             int* __restrict__ rowstart, int* __restrict__ cursor,
                             int* __restrict__ bcur) {
    int n = blockIdx.x * blockDim.x + threadIdx.x;
    if (n < NN) {
        int r = pre[n] + bsum[n >> 10];
        rowstart[n] = r;
        cursor[n] = r;
        if ((n & 1023) == 0) bcur[n >> 10] = r;
    }
    if (n == 0) rowstart[NN] = NE;
}

// ---- phase A: partition edges into buckets by dst>>10 (coalesced-ish writes) ----
__global__ void partA_kernel(const int* __restrict__ src, const int* __restrict__ dst,
                             int* __restrict__ bcur, int* __restrict__ bsrc,
                             int* __restrict__ bdst) {
    __shared__ int hist[NBK];
    __shared__ int lofs[NBK];
    int t = threadIdx.x;
    int base = blockIdx.x * CHUNK;
    int end = min(base + CHUNK, NE);
    if (t < NBK) hist[t] = 0;
    __syncthreads();
    for (int e = base + t; e < end; e += 256)
        atomicAdd(&hist[dst[e] >> 10], 1);
    __syncthreads();
    if (t < NBK) lofs[t] = atomicAdd(&bcur[t], hist[t]);
    __syncthreads();
    for (int e = base + t; e < end; e += 256) {
        int d = dst[e], s = src[e];
        int p = atomicAdd(&lofs[d >> 10], 1);
        bsrc[p] = s;
        bdst[p] = d;
    }
}

// ---- phase B: exact bin from bucket-ordered edges (L2-local scatter) ----
__global__ void binB_kernel(const int* __restrict__ bsrc, const int* __restrict__ bdst,
                            int* __restrict__ cursor, int* __restrict__ srcidx) {
    int e = blockIdx.x * blockDim.x + threadIdx.x;
    if (e >= NE) return;
    int d = bdst[e];
    int p = atomicAdd(&cursor[d], 1);
    srcidx[p] = bsrc[e];
}

// ---- fc1: hs[n,j] = relu(x@W + b) * dinv[n]  (pre-scaled activations) ----
__global__ void fc1_kernel(const float* __restrict__ x, const float* __restrict__ W,
                           const float* __restrict__ b, const float* __restrict__ dinv,
                           float* __restrict__ hs) {
    int gid = blockIdx.x * blockDim.x + threadIdx.x;
    if (gid >= NN * HID) return;
    int n = gid >> 5, j = gid & 31;
    float v = x[2 * n] * W[j] + x[2 * n + 1] * W[HID + j] + b[j];
    hs[gid] = fmaxf(v, 0.f) * dinv[n];
}

// ---- fused conv: agg = dinv[n]*(hs[n]+sum hs[s]); out = relu(agg@W + b) [*dinv] ----
template <bool OUTSCALE>
__global__ void conv_fused_kernel(const float* __restrict__ hs_in,
                                  const int* __restrict__ rowstart,
                                  const int* __restrict__ srcidx,
                                  const float* __restrict__ dinv,
                                  const float* __restrict__ W,
                                  const float* __restrict__ bias,
                                  float* __restrict__ hs_out) {
    __shared__ float wl[HID * HID];
    __shared__ float agg[8][HID];
    int tid = threadIdx.x;
    int base = blockIdx.x * 256;
#pragma unroll
    for (int i = 0; i < 4; ++i) wl[tid + 256 * i] = W[tid + 256 * i];
    int ln = tid >> 5, j = tid & 31;
    int n = (base >> 5) + ln;
    float acc = hs_in[(n << 5) + j];  // self loop
    int beg = rowstart[n], end = rowstart[n + 1];
    for (int e = beg; e < end; ++e)
        acc += hs_in[(srcidx[e] << 5) + j];
    agg[ln][j] = acc * dinv[n];
    __syncthreads();
    float v = 0.f;
#pragma unroll
    for (int k = 0; k < HID; ++k) v += agg[ln][k] * wl[k * HID + j];
    v = fmaxf(v + bias[j], 0.f);
    if (OUTSCALE) v *= dinv[n];
    hs_out[(n << 5) + j] = v;
}

// ---- fused fc2+fc3: v = relu(h@W2+b2); out[n] = sum_j v[j]*W3[j] + b3 ----
__global__ void fc23_kernel(const float* __restrict__ h, const float* __restrict__ W2,
                            const float* __restrict__ b2, const float* __restrict__ W3,
                            const float* __restrict__ b3, float* __restrict__ out) {
    __shared__ float wl[HID * HID];
    __shared__ float hsl[256];
    int tid = threadIdx.x;
    int base = blockIdx.x * 256;
#pragma unroll
    for (int i = 0; i < 4; ++i) wl[tid + 256 * i] = W2[tid + 256 * i];
    hsl[tid] = h[base + tid];
    __syncthreads();
    int ln = tid >> 5, j = tid & 31;
    float v = 0.f;
#pragma unroll
    for (int k = 0; k < HID; ++k) v += hsl[ln * HID + k] * wl[k * HID + j];
    v = fmaxf(v + b2[j], 0.f);
    float p = v * W3[j];
#pragma unroll
    for (int m = 16; m; m >>= 1) p += __shfl_xor(p, m);
    if (j == 0) out[(base >> 5) + ln] = p + b3[0];
}

extern "C" void kernel_launch(void* const* d_in, const int* in_sizes, int n_in,
                              void* d_out, int out_size, void* d_ws, size_t ws_size,
                              hipStream_t stream) {
    const float* x     = (const float*)d_in[0];
    const int*   ei    = (const int*)d_in[1];
    const float* fc1_W = (const float*)d_in[2];
    const float* fc1_b = (const float*)d_in[3];
    const float* c1_W  = (const float*)d_in[4];
    const float* c1_b  = (const float*)d_in[5];
    const float* c2_W  = (const float*)d_in[6];
    const float* c2_b  = (const float*)d_in[7];
    const float* c3_W  = (const float*)d_in[8];
    const float* c3_b  = (const float*)d_in[9];
    const float* fc2_W = (const float*)d_in[10];
    const float* fc2_b = (const float*)d_in[11];
    const float* fc3_W = (const float*)d_in[12];
    const float* fc3_b = (const float*)d_in[13];

    const int* src = ei;
    const int* dst = ei + NE;

    // workspace layout
    float* ws       = (float*)d_ws;
    float* dinv     = ws;                      // NN
    int*   deg      = (int*)(ws + NN);         // NN
    float* hA       = ws + 2 * NN;             // NN*32
    float* hB       = hA + NN * HID;           // NN*32
    int*   rowstart = (int*)(hB + NN * HID);   // NN+1
    int*   cursor   = rowstart + NN + 1;       // NN
    int*   pre      = cursor + NN;             // NN
    int*   bsum     = pre + NN;                // 128
    int*   bcur     = bsum + 128;              // 128
    int*   srcidx   = bcur + 128;              // NE
    // CSR-build scratch aliases h buffers (build precedes fc1)
    int*   bsrc     = (int*)hA;                // NE
    int*   bdst     = (int*)hB;                // NE

    float* out = (float*)d_out;

    const int B = 256;
    const int gN  = (NN + B - 1) / B;
    const int gNH = (NN * HID + B - 1) / B;    // 12500
    const int gE  = (NE + B - 1) / B;
    const int nScanBlk = (NN + 1023) / 1024;   // 98
    const int gPart = (NE + CHUNK - 1) / CHUNK;

    // ---- build CSR (bucketed two-phase binning) ----
    hipMemsetAsync(deg, 0, NN * sizeof(int), stream);
    count_deg_kernel<<<gE, B, 0, stream>>>(dst, deg);
    dinv_kernel<<<gN, B, 0, stream>>>(deg, dinv);
    scan1_kernel<<<nScanBlk, 256, 0, stream>>>(deg, pre, bsum);
    scan2_kernel<<<1, 128, 0, stream>>>(bsum, nScanBlk);
    scan3_kernel<<<gN, B, 0, stream>>>(pre, bsum, rowstart, cursor, bcur);
    partA_kernel<<<gPart, B, 0, stream>>>(src, dst, bcur, bsrc, bdst);
    binB_kernel<<<gE, B, 0, stream>>>(bsrc, bdst, cursor, srcidx);

    // fc1 -> hA (pre-scaled by dinv)
    fc1_kernel<<<gNH, B, 0, stream>>>(x, fc1_W, fc1_b, dinv, hA);

    // conv1..3 (fused gather+GEMM)
    conv_fused_kernel<true><<<gNH, B, 0, stream>>>(hA, rowstart, srcidx, dinv, c1_W, c1_b, hB);
    conv_fused_kernel<true><<<gNH, B, 0, stream>>>(hB, rowstart, srcidx, dinv, c2_W, c2_b, hA);
    conv_fused_kernel<false><<<gNH, B, 0, stream>>>(hA, rowstart, srcidx, dinv, c3_W, c3_b, hB);

    // fc2+fc3 -> out
    fc23_kernel<<<gNH, B, 0, stream>>>(hB, fc2_W, fc2_b, fc3_W, fc3_b, out);
}

// Round 4
// 228.727 us; speedup vs baseline: 2.9959x; 2.0111x over previous
//
#include <hip/hip_runtime.h>

#define NN 100000
#define NE 1600000
#define HID 32
#define NBK 98        // ceil(NN/1024) buckets of 1024 nodes
#define CHUNK 4096    // edges per partition block

// ---- count edges per 1024-node bucket (LDS hist -> global atomics) ----
__global__ void bucket_count_kernel(const int* __restrict__ dst, int* __restrict__ bktcnt) {
    __shared__ int hist[NBK];
    int t = threadIdx.x;
    int base = blockIdx.x * CHUNK;
    int end = min(base + CHUNK, NE);
    if (t < NBK) hist[t] = 0;
    __syncthreads();
    for (int e = base + t; e < end; e += 256)
        atomicAdd(&hist[dst[e] >> 10], 1);
    __syncthreads();
    if (t < NBK && hist[t]) atomicAdd(&bktcnt[t], hist[t]);
}

// ---- exclusive scan of 98 bucket counts ----
__global__ void bucket_scan_kernel(const int* __restrict__ bktcnt, int* __restrict__ bktbase,
                                   int* __restrict__ bktcur) {
    __shared__ int ls[128];
    int t = threadIdx.x;
    int v = (t < NBK) ? bktcnt[t] : 0;
    ls[t] = v;
    __syncthreads();
    for (int off = 1; off < 128; off <<= 1) {
        int x = (t >= off) ? ls[t - off] : 0;
        __syncthreads();
        ls[t] += x;
        __syncthreads();
    }
    int excl = ls[t] - v;
    if (t < NBK) { bktbase[t] = excl; bktcur[t] = excl; }
    if (t == 0) bktbase[NBK] = NE;
}

// ---- partition edges into bucket-ordered packed (src,dst) array ----
__global__ void partA_kernel(const int* __restrict__ src, const int* __restrict__ dst,
                             int* __restrict__ bktcur, int2* __restrict__ bedges) {
    __shared__ int hist[NBK];
    __shared__ int lofs[NBK];
    int t = threadIdx.x;
    int base = blockIdx.x * CHUNK;
    int end = min(base + CHUNK, NE);
    if (t < NBK) hist[t] = 0;
    __syncthreads();
    for (int e = base + t; e < end; e += 256)
        atomicAdd(&hist[dst[e] >> 10], 1);
    __syncthreads();
    if (t < NBK) lofs[t] = hist[t] ? atomicAdd(&bktcur[t], hist[t]) : 0;
    __syncthreads();
    for (int e = base + t; e < end; e += 256) {
        int d = dst[e], s = src[e];
        int p = atomicAdd(&lofs[d >> 10], 1);
        bedges[p] = make_int2(s, d);
    }
}

// ---- per-bucket: LDS degree hist -> LDS scan -> rowstart/dinv -> LDS-cursor binning ----
__global__ void bucket_build_kernel(const int2* __restrict__ bedges,
                                    const int* __restrict__ bktbase,
                                    int* __restrict__ rowstart, float* __restrict__ dinv,
                                    int* __restrict__ srcidx) {
    __shared__ int ldeg[1024];
    __shared__ int lcur[1024];
    __shared__ int wsum[512];
    int b = blockIdx.x, t = threadIdx.x;
    int n0 = b << 10;
    int ebeg = bktbase[b], eend = bktbase[b + 1];
    ldeg[t] = 0;
    ldeg[t + 512] = 0;
    __syncthreads();
    for (int e = ebeg + t; e < eend; e += 512)
        atomicAdd(&ldeg[bedges[e].y & 1023], 1);
    __syncthreads();
    // exclusive scan of 1024 degrees (thread t owns elems 2t, 2t+1)
    int a0 = ldeg[2 * t], a1 = ldeg[2 * t + 1];
    int s = a0 + a1;
    wsum[t] = s;
    __syncthreads();
    for (int off = 1; off < 512; off <<= 1) {
        int x = (t >= off) ? wsum[t - off] : 0;
        __syncthreads();
        wsum[t] += x;
        __syncthreads();
    }
    int excl = wsum[t] - s;
    lcur[2 * t] = excl;
    lcur[2 * t + 1] = excl + a0;
    int n = n0 + 2 * t;
    if (n < NN)     { rowstart[n] = ebeg + excl;      dinv[n] = rsqrtf((float)(a0 + 1)); }
    if (n + 1 < NN) { rowstart[n + 1] = ebeg + excl + a0; dinv[n + 1] = rsqrtf((float)(a1 + 1)); }
    if (b == 0 && t == 0) rowstart[NN] = NE;
    __syncthreads();
    for (int e = ebeg + t; e < eend; e += 512) {
        int2 ed = bedges[e];
        int p = atomicAdd(&lcur[ed.y & 1023], 1);
        srcidx[ebeg + p] = ed.x;
    }
}

// ---- fc1: hs[n,j] = relu(x@W + b) * dinv[n]  (pre-scaled activations) ----
__global__ void fc1_kernel(const float* __restrict__ x, const float* __restrict__ W,
                           const float* __restrict__ b, const float* __restrict__ dinv,
                           float* __restrict__ hs) {
    int gid = blockIdx.x * blockDim.x + threadIdx.x;
    if (gid >= NN * HID) return;
    int n = gid >> 5, j = gid & 31;
    float v = x[2 * n] * W[j] + x[2 * n + 1] * W[HID + j] + b[j];
    hs[gid] = fmaxf(v, 0.f) * dinv[n];
}

// ---- fused conv: wave-per-node-pair gather (8 edge-slots x 8 float4 lanes) + LDS GEMM ----
template <bool OUTSCALE>
__global__ void conv_fused_kernel(const float* __restrict__ hs_in,
                                  const int* __restrict__ rowstart,
                                  const int* __restrict__ srcidx,
                                  const float* __restrict__ dinv,
                                  const float* __restrict__ W,
                                  const float* __restrict__ bias,
                                  float* __restrict__ hs_out) {
    __shared__ float wl[HID * HID];
    __shared__ float agg[8][HID];
    int tid = threadIdx.x;
    int base8 = blockIdx.x * 8;  // first node of this block
#pragma unroll
    for (int i = 0; i < 4; ++i) wl[tid + 256 * i] = W[tid + 256 * i];
    int wave = tid >> 6, lane = tid & 63;
    int g = lane >> 3;   // edge slot 0..7
    int l = lane & 7;    // channel quad 0..7
#pragma unroll
    for (int rep = 0; rep < 2; ++rep) {
        int ln = wave * 2 + rep;
        int n = base8 + ln;
        int beg = rowstart[n], end = rowstart[n + 1];
        float4 acc0 = make_float4(0.f, 0.f, 0.f, 0.f);
        float4 acc1 = make_float4(0.f, 0.f, 0.f, 0.f);
        int e = beg + g;
        for (; e + 8 < end; e += 16) {
            int s0 = srcidx[e];
            int s1 = srcidx[e + 8];
            float4 v0 = *(const float4*)&hs_in[(s0 << 5) + (l << 2)];
            float4 v1 = *(const float4*)&hs_in[(s1 << 5) + (l << 2)];
            acc0.x += v0.x; acc0.y += v0.y; acc0.z += v0.z; acc0.w += v0.w;
            acc1.x += v1.x; acc1.y += v1.y; acc1.z += v1.z; acc1.w += v1.w;
        }
        if (e < end) {
            int s0 = srcidx[e];
            float4 v0 = *(const float4*)&hs_in[(s0 << 5) + (l << 2)];
            acc0.x += v0.x; acc0.y += v0.y; acc0.z += v0.z; acc0.w += v0.w;
        }
        acc0.x += acc1.x; acc0.y += acc1.y; acc0.z += acc1.z; acc0.w += acc1.w;
#pragma unroll
        for (int m = 8; m < 64; m <<= 1) {
            acc0.x += __shfl_xor(acc0.x, m);
            acc0.y += __shfl_xor(acc0.y, m);
            acc0.z += __shfl_xor(acc0.z, m);
            acc0.w += __shfl_xor(acc0.w, m);
        }
        if (g == 0) {
            float4 self = *(const float4*)&hs_in[(n << 5) + (l << 2)];
            float dv = dinv[n];
            float4 r;
            r.x = (acc0.x + self.x) * dv;
            r.y = (acc0.y + self.y) * dv;
            r.z = (acc0.z + self.z) * dv;
            r.w = (acc0.w + self.w) * dv;
            *(float4*)&agg[ln][l << 2] = r;
        }
    }
    __syncthreads();
    int ln = tid >> 5, j = tid & 31;
    int n = base8 + ln;
    float v = 0.f;
#pragma unroll
    for (int k = 0; k < HID; ++k) v += agg[ln][k] * wl[k * HID + j];
    v = fmaxf(v + bias[j], 0.f);
    if (OUTSCALE) v *= dinv[n];
    hs_out[(n << 5) + j] = v;
}

// ---- fused fc2+fc3 ----
__global__ void fc23_kernel(const float* __restrict__ h, const float* __restrict__ W2,
                            const float* __restrict__ b2, const float* __restrict__ W3,
                            const float* __restrict__ b3, float* __restrict__ out) {
    __shared__ float wl[HID * HID];
    __shared__ float hsl[256];
    int tid = threadIdx.x;
    int base = blockIdx.x * 256;
#pragma unroll
    for (int i = 0; i < 4; ++i) wl[tid + 256 * i] = W2[tid + 256 * i];
    hsl[tid] = h[base + tid];
    __syncthreads();
    int ln = tid >> 5, j = tid & 31;
    float v = 0.f;
#pragma unroll
    for (int k = 0; k < HID; ++k) v += hsl[ln * HID + k] * wl[k * HID + j];
    v = fmaxf(v + b2[j], 0.f);
    float p = v * W3[j];
#pragma unroll
    for (int m = 16; m; m >>= 1) p += __shfl_xor(p, m);
    if (j == 0) out[(base >> 5) + ln] = p + b3[0];
}

extern "C" void kernel_launch(void* const* d_in, const int* in_sizes, int n_in,
                              void* d_out, int out_size, void* d_ws, size_t ws_size,
                              hipStream_t stream) {
    const float* x     = (const float*)d_in[0];
    const int*   ei    = (const int*)d_in[1];
    const float* fc1_W = (const float*)d_in[2];
    const float* fc1_b = (const float*)d_in[3];
    const float* c1_W  = (const float*)d_in[4];
    const float* c1_b  = (const float*)d_in[5];
    const float* c2_W  = (const float*)d_in[6];
    const float* c2_b  = (const float*)d_in[7];
    const float* c3_W  = (const float*)d_in[8];
    const float* c3_b  = (const float*)d_in[9];
    const float* fc2_W = (const float*)d_in[10];
    const float* fc2_b = (const float*)d_in[11];
    const float* fc3_W = (const float*)d_in[12];
    const float* fc3_b = (const float*)d_in[13];

    const int* src = ei;
    const int* dst = ei + NE;

    // workspace layout
    float* ws       = (float*)d_ws;
    float* dinv     = ws;                        // NN
    float* hA       = ws + NN;                   // NN*32
    float* hB       = hA + NN * HID;             // NN*32
    int*   rowstart = (int*)(hB + NN * HID);     // NN+1
    int*   srcidx   = rowstart + NN + 1;         // NE
    int*   bktcnt   = srcidx + NE;               // NBK
    int*   bktbase  = bktcnt + NBK;              // NBK+1
    int*   bktcur   = bktbase + NBK + 1;         // NBK
    int2*  bedges   = (int2*)hA;                 // NE int2 (aliases hA; used pre-fc1)

    float* out = (float*)d_out;

    const int B = 256;
    const int gNH = (NN * HID + B - 1) / B;      // 12500
    const int gPart = (NE + CHUNK - 1) / CHUNK;  // 391

    // ---- build CSR (bucket-local, LDS atomics only on hot paths) ----
    hipMemsetAsync(bktcnt, 0, NBK * sizeof(int), stream);
    bucket_count_kernel<<<gPart, B, 0, stream>>>(dst, bktcnt);
    bucket_scan_kernel<<<1, 128, 0, stream>>>(bktcnt, bktbase, bktcur);
    partA_kernel<<<gPart, B, 0, stream>>>(src, dst, bktcur, bedges);
    bucket_build_kernel<<<NBK, 512, 0, stream>>>(bedges, bktbase, rowstart, dinv, srcidx);

    // fc1 -> hA (pre-scaled by dinv)
    fc1_kernel<<<gNH, B, 0, stream>>>(x, fc1_W, fc1_b, dinv, hA);

    // conv1..3 (fused gather+GEMM)
    conv_fused_kernel<true><<<gNH, B, 0, stream>>>(hA, rowstart, srcidx, dinv, c1_W, c1_b, hB);
    conv_fused_kernel<true><<<gNH, B, 0, stream>>>(hB, rowstart, srcidx, dinv, c2_W, c2_b, hA);
    conv_fused_kernel<false><<<gNH, B, 0, stream>>>(hA, rowstart, srcidx, dinv, c3_W, c3_b, hB);

    // fc2+fc3 -> out
    fc23_kernel<<<gNH, B, 0, stream>>>(hB, fc2_W, fc2_b, fc3_W, fc3_b, out);
}